// Round 9
// baseline (2467.448 us; speedup 1.0000x reference)
//
#include <hip/hip_runtime.h>
#include <hip/hip_fp16.h>

typedef unsigned int u32;
typedef unsigned long long u64;

// ---------------- workspace layout (bytes) ----------------
static constexpr size_t OFF_X2    = 0;          // X2h [8192][320] f16 (dead after pre-gemm)
static constexpr size_t OFF_PRE   = 9830400;    // pre [8192][4096] f16 (dead after scan)
// scan-time overlays inside X2 region (X2h dead by then):
static constexpr size_t OFF_MB    = 131072;     // mask bits [256] u32
static constexpr size_t OFF_FLG   = 135168;     // flags [257][128] u32 = 131584 B
// post-scan overlays:
static constexpr size_t OFF_TOUT  = 0;          // text_out [32][256][512] f32
static constexpr size_t OFF_TOUTT = 16777216;   // tOutT    [32][512][256] f32
static constexpr size_t OFF_PWT   = 33554432;   // pw_text  [32][256][512] f32
static constexpr size_t OFF_PWTTH = 50331648;   // pwtT_hi [32][512][256] f16 = 8MB
static constexpr size_t OFF_PWTTL = 58720256;   // pwtT_lo [32][512][256] f16 = 8MB
static constexpr size_t OFF_Y     = 76939264;   // y [2][32][256][512] f32 (dead after fuse_ct)
static constexpr size_t OFF_AGG0  = 76939264;   // agg0 f32 (overlays dead y)
static constexpr size_t OFF_GCWT  = 93716480;   // gcw0T hi/lo (overlays dead y)
static constexpr size_t OFF_PWX   = 110493696;  // pwx f32; during scan: Hs[256][2][32][128]u64 = 16MB
static constexpr size_t OFF_WD    = 127270912;  // Wmf packed fp16 whh A-frags = 4MB
static constexpr size_t OFF_WIH   = 131465216;  // wihh [4096][320] f16
static constexpr size_t OFF_BIA   = 136380416;  // biascat [4096] f32
static constexpr size_t OFF_W1T   = 136396800;  // w1T [3][512][512] f32
static constexpr size_t OFF_W2T   = 139542528;  // w2T [3][512][512] f32
static constexpr size_t OFF_META  = 142688256;  // int a0[32],a1[32],nm[32],tl[32]
static constexpr size_t OFF_CLF   = 142688768;  // float cl[32]
static constexpr size_t OFF_DEN   = 142688896;  // denom [32][256] f32
static constexpr size_t OFF_POSW  = 142721664;  // posw  [32][256] f32
static constexpr size_t OFF_AGGM  = 142754432;  // aggm [32][4][512] f32
static constexpr size_t OFF_GMSK  = 143016576;  // gmask [32][4][512] f32
static constexpr size_t OFF_C1PW  = 143278720;  // c1pw [32][6][512] f32
static constexpr size_t OFF_XC2   = 143671936;  // xc2 [32][4][512] f32
static constexpr size_t OFF_AVEC  = 143934080;  // avec [3][32][512] f32
static constexpr size_t WS_NEED   = 144130688;

__device__ __forceinline__ float sigf(float x) { return 1.f / (1.f + expf(-x)); }

typedef _Float16 half8 __attribute__((ext_vector_type(8)));
typedef float f32x4 __attribute__((ext_vector_type(4)));
union U4H8 { uint4 u; half8 h; };

__device__ __forceinline__ u32 packh2(float a, float b) {
    return (u32)__half_as_ushort(__float2half(a)) |
           ((u32)__half_as_ushort(__float2half(b)) << 16);
}

// ---------------- lengths / meta ----------------
__global__ void len_k(const int* __restrict__ ti, const int* __restrict__ ai,
                      const int* __restrict__ li, int* __restrict__ meta, float* __restrict__ clf)
{
    int b = threadIdx.x;
    if (b >= 32) return;
    int tl = 0;
    for (int s = 0; s < 256; ++s) tl += (ti[b*256+s] != 0);
    int al = 0;
    for (int i = 0; i < 4; ++i) al += (ai[b*4+i] != 0);
    int ll = 0;
    for (int i = 0; i < 16; ++i) ll += (li[b*16+i] != 0);
    meta[b]      = ll;
    meta[32+b]   = ll + al - 1;
    meta[64+b]   = al;
    meta[96+b]   = tl;
    clf[b] = (float)(tl - al);
}

// ---------------- denom + pos-weight ----------------
__global__ __launch_bounds__(256)
void pd_k(const float* __restrict__ adj, const int* __restrict__ meta,
          const float* __restrict__ clf, float* __restrict__ denom, float* __restrict__ posw)
{
    int row = blockIdx.x;            // b*256+s
    int b = row >> 8, s = row & 255;
    int tid = threadIdx.x;
    float v = adj[(size_t)row*256 + tid];
    #pragma unroll
    for (int off = 1; off < 64; off <<= 1) v += __shfl_xor(v, off);
    __shared__ float rd[4];
    if ((tid & 63) == 0) rd[tid >> 6] = v;
    __syncthreads();
    if (tid == 0) {
        denom[row] = rd[0] + rd[1] + rd[2] + rd[3] + 1.f;
        int a0 = meta[b], a1 = meta[32+b], tl = meta[96+b];
        float cl = clf[b];
        float w;
        if (s < a0)       w = 1.f - (float)(a0 - s) / cl;
        else if (s <= a1) w = 0.f;
        else if (s < tl)  w = 1.f - (float)(s - a1) / cl;
        else              w = 0.f;
        posw[row] = w;
    }
}

// ---------------- embedding gather ----------------
__global__ __launch_bounds__(128)
void gather_k(const int* __restrict__ ti, const float* __restrict__ emb, __half* __restrict__ X2h)
{
    int row = blockIdx.x;            // s*32+b
    int b = row & 31, s = row >> 5;
    int idx = ti[b*256 + s];
    const float* e = emb + (size_t)idx*300;
    __half* o = X2h + (size_t)row*320;
    for (int k = threadIdx.x; k < 320; k += 128)
        o[k] = (k < 300) ? __float2half(e[k]) : __ushort_as_half((unsigned short)0);
}

// ---------------- pack wih -> f16 rows ----------------
__global__ __launch_bounds__(256)
void wpackih_k(const float* __restrict__ wf, const float* __restrict__ wb, u32* __restrict__ Wih)
{
    u32 idx = blockIdx.x*256 + threadIdx.x;
    if (idx >= 655360u) return;
    int n = idx / 160;
    int j = idx - n*160;
    int k0 = 2*j;
    const float* w = (n < 2048) ? (wf + (size_t)n*300) : (wb + (size_t)(n - 2048)*300);
    float v0 = (k0   < 300) ? w[k0]   : 0.f;
    float v1 = (k0+1 < 300) ? w[k0+1] : 0.f;
    Wih[idx] = packh2(v0, v1);
}

// ---------------- pack whh -> MFMA A-fragment layout ----------------
__global__ __launch_bounds__(256)
void wmf_k(const float* __restrict__ wf, const float* __restrict__ wb, u32* __restrict__ Wmf)
{
    u32 idx = blockIdx.x*256 + threadIdx.x;   // < 1,048,576
    int e2 = idx & 3;
    int l  = (idx >> 2) & 63;
    int c  = (idx >> 8) & 3;
    int mt = (idx >> 10) & 1;
    int wv = (idx >> 11) & 3;
    int g  = (idx >> 13) & 63;
    int dir = (int)(idx >> 19);
    int kloc = wv*128 + c*32 + 16*(e2 >> 1) + 4*(l >> 4) + 2*(e2 & 1);
    int ml = mt*16 + (l & 15);
    int n = (ml & 3)*512 + g*8 + (ml >> 2);
    const float* w = dir ? wb : wf;
    Wmf[idx] = packh2(w[(size_t)n*512 + kloc], w[(size_t)n*512 + kloc + 1]);
}

// ---------------- mask bits ----------------
__global__ void maskb_k(const int* __restrict__ ti, u32* __restrict__ mb)
{
    int s = threadIdx.x;
    u32 w = 0;
    for (int b = 0; b < 32; ++b) w |= (u32)(ti[b*256 + s] != 0) << b;
    mb[s] = w;
}

// ---------------- conv weight transpose ----------------
__global__ __launch_bounds__(256)
void wtrans_k(const float* __restrict__ w1, const float* __restrict__ w2,
              float* __restrict__ w1T, float* __restrict__ w2T)
{
    u32 idx = blockIdx.x*256 + threadIdx.x;
    const float* src = blockIdx.y ? w2 : w1;
    float* dst = blockIdx.y ? w2T : w1T;
    int k = idx >> 18;
    int i = (idx >> 9) & 511;
    int o = idx & 511;
    dst[idx] = src[((size_t)o*512 + i)*3 + k];
}

// ---------------- pack gcw[0]^T -> f16 hi/lo ----------------
__global__ __launch_bounds__(256)
void wpackg_k(const float* __restrict__ gcw, u32* __restrict__ Ghi, u32* __restrict__ Glo)
{
    u32 idx = blockIdx.x*256 + threadIdx.x;   // < 131072
    int n = idx >> 8, k2 = idx & 255;
    float v0 = gcw[(size_t)(2*k2)*512 + n];
    float v1 = gcw[(size_t)(2*k2 + 1)*512 + n];
    __half h0 = __float2half(v0), h1 = __float2half(v1);
    Ghi[idx] = (u32)__half_as_ushort(h0) | ((u32)__half_as_ushort(h1) << 16);
    Glo[idx] = packh2(v0 - __half2float(h0), v1 - __half2float(h1));
}

// ---------------- MFMA pre-activation GEMM ----------------
__global__ __launch_bounds__(256)
void pre_mfma_k(const u32* __restrict__ X2u, const u32* __restrict__ Wihu,
                const float* __restrict__ bias, __half* __restrict__ pre)
{
    __shared__ u32 As2[16*132];
    __shared__ u32 Bs2[16*132];
    const int tid = threadIdx.x;
    const int wv = tid >> 6;
    const int l  = tid & 63;
    const int q  = l >> 4;
    const int l15 = l & 15;
    const int wm = wv & 1, wn = wv >> 1;
    const int m0 = blockIdx.x * 128;
    const int n0 = blockIdx.y * 128;

    f32x4 acc[4][4];
    #pragma unroll
    for (int mt = 0; mt < 4; ++mt)
        #pragma unroll
        for (int nt = 0; nt < 4; ++nt)
            acc[mt][nt] = (f32x4){0.f, 0.f, 0.f, 0.f};

    const int srow = tid >> 4;
    const int sj   = tid & 15;

    for (int kb = 0; kb < 10; ++kb) {
        #pragma unroll
        for (int i = 0; i < 8; ++i) {
            int row = srow + i*16;
            As2[sj*132 + row] = X2u[(size_t)(m0 + row)*160 + kb*16 + sj];
            Bs2[sj*132 + row] = Wihu[(size_t)(n0 + row)*160 + kb*16 + sj];
        }
        __syncthreads();

        U4H8 bf[4];
        #pragma unroll
        for (int nt = 0; nt < 4; ++nt) {
            int col = wn*64 + nt*16 + l15;
            bf[nt].u = make_uint4(Bs2[(2*q)*132 + col], Bs2[(2*q+1)*132 + col],
                                  Bs2[(2*q+8)*132 + col], Bs2[(2*q+9)*132 + col]);
        }
        #pragma unroll
        for (int mt = 0; mt < 4; ++mt) {
            int row = wm*64 + mt*16 + l15;
            U4H8 af;
            af.u = make_uint4(As2[(2*q)*132 + row], As2[(2*q+1)*132 + row],
                              As2[(2*q+8)*132 + row], As2[(2*q+9)*132 + row]);
            #pragma unroll
            for (int nt = 0; nt < 4; ++nt)
                acc[mt][nt] = __builtin_amdgcn_mfma_f32_16x16x32_f16(af.h, bf[nt].h, acc[mt][nt], 0, 0, 0);
        }
        __syncthreads();
    }

    #pragma unroll
    for (int nt = 0; nt < 4; ++nt) {
        int col = n0 + wn*64 + nt*16 + l15;
        float bv = bias[col];
        #pragma unroll
        for (int mt = 0; mt < 4; ++mt) {
            int rbase = m0 + wm*64 + mt*16 + q*4;
            #pragma unroll
            for (int p = 0; p < 4; ++p)
                pre[(size_t)(rbase + p)*4096 + col] = __float2half(acc[mt][nt][p] + bv);
        }
    }
}

// ---------------- generic hi/lo-split MFMA GEMM ----------------
template<int SPLITA, int EPI>
__global__ __launch_bounds__(256)
void mmsplit_k(const float* __restrict__ A, const u32* __restrict__ Bhi,
               const u32* __restrict__ Blo, float* __restrict__ C,
               int N, int Ku32, long sA, long sB, long sC,
               const float* __restrict__ bias, const float* __restrict__ denom,
               const float* __restrict__ posw)
{
    __shared__ u32 Ah[16*132];
    __shared__ u32 Al[16*132];
    __shared__ u32 Bh[16*132];
    __shared__ u32 Bl[16*132];
    const int z = blockIdx.z;
    A   += (size_t)z * sA;
    Bhi += (size_t)z * sB;
    Blo += (size_t)z * sB;
    C   += (size_t)z * sC;
    const int m0 = blockIdx.x * 128;
    const int n0 = blockIdx.y * 128;
    const int tid = threadIdx.x;
    const int wv = tid >> 6;
    const int l  = tid & 63;
    const int q  = l >> 4;
    const int l15 = l & 15;
    const int wm = wv & 1, wn = wv >> 1;
    const int pitchA = 2*Ku32;

    f32x4 acc[4][4];
    #pragma unroll
    for (int mt = 0; mt < 4; ++mt)
        #pragma unroll
        for (int nt = 0; nt < 4; ++nt)
            acc[mt][nt] = (f32x4){0.f, 0.f, 0.f, 0.f};

    const int srow = tid >> 4;
    const int sj   = tid & 15;
    const int nkb = Ku32 >> 4;

    for (int kb = 0; kb < nkb; ++kb) {
        #pragma unroll
        for (int i = 0; i < 8; ++i) {
            int row = srow + i*16;
            float2 av = *(const float2*)(A + (size_t)(m0 + row)*pitchA + kb*32 + 2*sj);
            __half h0 = __float2half(av.x), h1 = __float2half(av.y);
            Ah[sj*132 + row] = (u32)__half_as_ushort(h0) | ((u32)__half_as_ushort(h1) << 16);
            if (SPLITA)
                Al[sj*132 + row] = packh2(av.x - __half2float(h0), av.y - __half2float(h1));
            Bh[sj*132 + row] = Bhi[(size_t)(n0 + row)*Ku32 + kb*16 + sj];
            Bl[sj*132 + row] = Blo[(size_t)(n0 + row)*Ku32 + kb*16 + sj];
        }
        __syncthreads();

        U4H8 bfh[4], bfl[4];
        #pragma unroll
        for (int nt = 0; nt < 4; ++nt) {
            int col = wn*64 + nt*16 + l15;
            bfh[nt].u = make_uint4(Bh[(2*q)*132 + col], Bh[(2*q+1)*132 + col],
                                   Bh[(2*q+8)*132 + col], Bh[(2*q+9)*132 + col]);
            bfl[nt].u = make_uint4(Bl[(2*q)*132 + col], Bl[(2*q+1)*132 + col],
                                   Bl[(2*q+8)*132 + col], Bl[(2*q+9)*132 + col]);
        }
        #pragma unroll
        for (int mt = 0; mt < 4; ++mt) {
            int row = wm*64 + mt*16 + l15;
            U4H8 afh;
            afh.u = make_uint4(Ah[(2*q)*132 + row], Ah[(2*q+1)*132 + row],
                               Ah[(2*q+8)*132 + row], Ah[(2*q+9)*132 + row]);
            #pragma unroll
            for (int nt = 0; nt < 4; ++nt) {
                acc[mt][nt] = __builtin_amdgcn_mfma_f32_16x16x32_f16(afh.h, bfh[nt].h, acc[mt][nt], 0, 0, 0);
                acc[mt][nt] = __builtin_amdgcn_mfma_f32_16x16x32_f16(afh.h, bfl[nt].h, acc[mt][nt], 0, 0, 0);
            }
            if (SPLITA) {
                U4H8 afl;
                afl.u = make_uint4(Al[(2*q)*132 + row], Al[(2*q+1)*132 + row],
                                   Al[(2*q+8)*132 + row], Al[(2*q+9)*132 + row]);
                #pragma unroll
                for (int nt = 0; nt < 4; ++nt)
                    acc[mt][nt] = __builtin_amdgcn_mfma_f32_16x16x32_f16(afl.h, bfh[nt].h, acc[mt][nt], 0, 0, 0);
            }
        }
        __syncthreads();
    }

    #pragma unroll
    for (int nt = 0; nt < 4; ++nt) {
        int col = n0 + wn*64 + nt*16 + l15;
        float bv = (EPI == 1) ? bias[col] : 0.f;
        #pragma unroll
        for (int mt = 0; mt < 4; ++mt) {
            int rbase = m0 + wm*64 + mt*16 + q*4;
            #pragma unroll
            for (int p = 0; p < 4; ++p) {
                int m = rbase + p;
                if (EPI == 0) {
                    C[(size_t)m*N + col] = acc[mt][nt][p];
                } else {
                    float v = fmaf(acc[mt][nt][p], 1.f/denom[m], bv);
                    C[(size_t)m*N + col] = fmaxf(v, 0.f) * posw[m];
                }
            }
        }
    }
}

// ---------------- persistent batched LSTM scan v7 ----------------
// 64 WGs x 256 thr; WG g owns h-cols 8g..8g+7 for BOTH directions; the two
// independent recurrences interleave so each dir's flag->poll L3 latency hides
// under the other dir's compute. Per-wave k-quarter decoupling: wave wv polls
// only its 16 producers, stages/MFMAs its own LDS quarter (no cross-wave dep);
// 2 barriers per dir-step. Exchange/flags machinery identical to v6.
__global__ __launch_bounds__(256, 1)
void lstm_scan7_k(const __half* __restrict__ pre, const u32* __restrict__ Wmf,
                  const u32* __restrict__ mb, float* __restrict__ y,
                  u32* __restrict__ flags, u64* __restrict__ Hs)
{
    __shared__ u32 hs[32*264];
    __shared__ float gred[4352];

    const int tid = threadIdx.x;
    const int wv = tid >> 6;            // wave = k-quarter
    const int l  = tid & 63;
    const int q  = l >> 4;
    const int l15 = l & 15;
    const int g  = blockIdx.x;          // 0..63
    const int b2 = tid >> 3;            // epilogue batch
    const int jj = tid & 7;             // epilogue h-col within WG
    const int gcol = g*8 + jj;
    const int ks64 = wv*64;
    const int sb = l >> 1;              // staging batch
    const int sh = l & 1;               // staging half of quarter

    // stationary A fragments, both dirs
    half8 afr[2][2][4];
    #pragma unroll
    for (int d = 0; d < 2; ++d) {
        const uint4* wp = (const uint4*)(Wmf + ((((size_t)d*64 + g)*4 + wv)*2048)) + l;
        #pragma unroll
        for (int mt = 0; mt < 2; ++mt)
            #pragma unroll
            for (int c = 0; c < 4; ++c)
                afr[d][mt][c] = __builtin_bit_cast(half8, wp[(mt*4 + c)*64]);
    }

    float hreg[2] = {0.f, 0.f}, creg[2] = {0.f, 0.f};
    __half ph[2][4];
    #pragma unroll
    for (int d = 0; d < 2; ++d) {
        int s0 = d ? 255 : 0;
        #pragma unroll
        for (int gt = 0; gt < 4; ++gt)
            ph[d][gt] = pre[((size_t)s0*32 + b2)*4096 + d*2048 + gt*512 + gcol];
    }
    u32 mbv[2] = {mb[0], mb[255]};

    for (int t = 0; t < 256; ++t) {
        const int bi  = (int)(__brev((u32)t) >> 24);
        const int bi2 = (int)(__brev((u32)(t + 1)) >> 24);

        #pragma unroll 1
        for (int d = 0; d < 2; ++d) {
            const int s = d ? (255 - t) : t;

            // acquire own k-quarter of h_prev (per-wave, no WG barrier)
            if (t == 0) {
                u32* dst = &hs[sb*264 + ks64 + sh*32];
                #pragma unroll
                for (int i = 0; i < 8; ++i) *(uint4*)(dst + i*4) = make_uint4(0u,0u,0u,0u);
            } else {
                u32 fv = 1u;
                u32* fp = flags + (size_t)t*128 + d*64 + wv*16 + (l & 15);
                if (l < 16)
                    fv = __hip_atomic_fetch_add(fp, 0u, __ATOMIC_RELAXED, __HIP_MEMORY_SCOPE_AGENT);
                int guard = 0;
                while (!__all(fv != 0u)) {
                    __builtin_amdgcn_s_sleep(1);
                    if (l < 16)
                        fv = __hip_atomic_fetch_add(fp, 0u, __ATOMIC_RELAXED, __HIP_MEMORY_SCOPE_AGENT);
                    if (++guard > (1 << 22)) break;   // visibility bug -> wrong result, not hang
                }
                const uint4* srcrow = (const uint4*)(Hs + ((size_t)(bi*2 + d)*32 + sb)*128)
                                      + wv*16 + sh*8;
                uint4 vv[8];
                #pragma unroll
                for (int i = 0; i < 8; ++i) vv[i] = srcrow[i];
                u32* dst = &hs[sb*264 + ks64 + sh*32];
                #pragma unroll
                for (int i = 0; i < 8; ++i) *(uint4*)(dst + i*4) = vv[i];
            }

            // MFMA over own k-quarter (reads only what this wave staged)
            f32x4 acc[2][2];
            #pragma unroll
            for (int mt = 0; mt < 2; ++mt)
                #pragma unroll
                for (int nt = 0; nt < 2; ++nt)
                    acc[mt][nt] = (f32x4){0.f, 0.f, 0.f, 0.f};
            #pragma unroll
            for (int c = 0; c < 4; ++c) {
                #pragma unroll
                for (int nt = 0; nt < 2; ++nt) {
                    int base = (nt*16 + l15)*264 + ks64 + c*16 + 2*q;
                    uint4 bw = make_uint4(hs[base], hs[base+1], hs[base+8], hs[base+9]);
                    half8 bfr = __builtin_bit_cast(half8, bw);
                    acc[0][nt] = __builtin_amdgcn_mfma_f32_16x16x32_f16(afr[d][0][c], bfr, acc[0][nt], 0, 0, 0);
                    acc[1][nt] = __builtin_amdgcn_mfma_f32_16x16x32_f16(afr[d][1][c], bfr, acc[1][nt], 0, 0, 0);
                }
            }
            #pragma unroll
            for (int mt = 0; mt < 2; ++mt)
                #pragma unroll
                for (int nt = 0; nt < 2; ++nt)
                    #pragma unroll
                    for (int p = 0; p < 4; ++p)
                        gred[(((wv*2 + mt)*2 + nt)*16 + q*4 + p)*17 + l15] = acc[mt][nt][p];
            __syncthreads();

            // epilogue: thread (b2, jj)
            float gv[4];
            #pragma unroll
            for (int gt = 0; gt < 4; ++gt) {
                int ml = 4*jj + gt;
                int mt = ml >> 4, r = ml & 15;
                int ntile = b2 >> 4, n = b2 & 15;
                float sum = 0.f;
                #pragma unroll
                for (int w2 = 0; w2 < 4; ++w2)
                    sum += gred[(((w2*2 + mt)*2 + ntile)*16 + r)*17 + n];
                gv[gt] = sum + __half2float(ph[d][gt]);
            }
            float cn = sigf(gv[1])*creg[d] + sigf(gv[0])*tanhf(gv[2]);
            float hn = sigf(gv[3])*tanhf(cn);
            bool mk = (mbv[d] >> b2) & 1u;
            if (mk) { hreg[d] = hn; creg[d] = cn; }

            // pack 4 h-cols -> u64, store into step-unique L3 buffer
            {
                int l4 = l & ~3;
                float h0 = __shfl(hreg[d], l4 + 0);
                float h1 = __shfl(hreg[d], l4 + 1);
                float h2 = __shfl(hreg[d], l4 + 2);
                float h3 = __shfl(hreg[d], l4 + 3);
                if ((tid & 3) == 0) {
                    u64 pk = (u64)packh2(h0, h1) | ((u64)packh2(h2, h3) << 32);
                    int wsel = (tid >> 2) & 1;
                    __hip_atomic_store(&Hs[((size_t)(bi2*2 + d)*32 + b2)*128 + 2*g + wsel], pk,
                                       __ATOMIC_RELAXED, __HIP_MEMORY_SCOPE_AGENT);
                }
            }
            asm volatile("s_waitcnt vmcnt(0)" ::: "memory");
            __syncthreads();
            if (tid == 0) {
                __hip_atomic_store(flags + (size_t)(t + 1)*128 + d*64 + g, 1u,
                                   __ATOMIC_RELAXED, __HIP_MEMORY_SCOPE_AGENT);
            }
            // y store off the critical path
            y[(((size_t)d*32 + b2)*256 + s)*512 + gcol] = mk ? hn : 0.f;
        }

        // prefetch next step's pre + mask, both dirs
        if (t < 255) {
            #pragma unroll
            for (int d = 0; d < 2; ++d) {
                int sn = d ? (254 - t) : (t + 1);
                #pragma unroll
                for (int gt = 0; gt < 4; ++gt)
                    ph[d][gt] = pre[((size_t)sn*32 + b2)*4096 + d*2048 + gt*512 + gcol];
            }
            mbv[0] = mb[t + 1];
            mbv[1] = mb[254 - t];
        }
    }
}

// ---------------- fused combine + transpose + pwtT hi/lo pack ----------------
__global__ __launch_bounds__(256)
void fuse_ct_k(const float* __restrict__ y, const float* __restrict__ posw,
               float* __restrict__ text_out, float* __restrict__ pw_text,
               float* __restrict__ tOutT, u32* __restrict__ pwtThi, u32* __restrict__ pwtTlo)
{
    __shared__ float tileV[32][33];
    __shared__ float tileP[32][33];
    int b = blockIdx.z, s0 = blockIdx.x*32, h0 = blockIdx.y*32;
    int tx = threadIdx.x & 31, ty4 = threadIdx.x >> 5;
    int hg = h0 + tx;
    #pragma unroll
    for (int rr = 0; rr < 4; ++rr) {
        int sy = ty4 + rr*8;
        int s = s0 + sy;
        const float* p;
        if (hg < 256) p = y + (((size_t)b*256 + s)*512 + 2*hg);
        else          p = y + (((size_t)(32 + b)*256 + s)*512 + 2*(hg - 256));
        float v = 0.5f*(p[0] + p[1]);
        float pw = v * posw[b*256 + s];
        text_out[((size_t)b*256 + s)*512 + hg] = v;
        pw_text [((size_t)b*256 + s)*512 + hg] = pw;
        tileV[sy][tx] = v;
        tileP[sy][tx] = pw;
    }
    __syncthreads();
    #pragma unroll
    for (int rr = 0; rr < 4; ++rr) {
        int hy = ty4 + rr*8;
        tOutT[((size_t)b*512 + h0 + hy)*256 + s0 + tx] = tileV[tx][hy];
    }
    for (int slot = threadIdx.x; slot < 512; slot += 256) {
        int hh = slot >> 4, sp = slot & 15;
        float p0 = tileP[2*sp][hh];
        float p1 = tileP[2*sp + 1][hh];
        __half q0 = __float2half(p0), q1 = __float2half(p1);
        size_t di = ((size_t)b*512 + h0 + hh)*128 + (s0 >> 1) + sp;
        pwtThi[di] = (u32)__half_as_ushort(q0) | ((u32)__half_as_ushort(q1) << 16);
        pwtTlo[di] = packh2(p0 - __half2float(q0), p1 - __half2float(q1));
    }
}

// ---------------- masked-row adj aggregation ----------------
__global__ __launch_bounds__(256)
void aggm_k(const float* __restrict__ adj, const float* __restrict__ pwx,
            const int* __restrict__ meta, float* __restrict__ aggm)
{
    int b = blockIdx.x >> 2, r = blockIdx.x & 3;
    int a0 = meta[b], nm = meta[64+b];
    int s = a0 + r; if (s > 255) s = 255;
    __shared__ float arow[256];
    int tid = threadIdx.x;
    arow[tid] = adj[((size_t)b*256 + s)*256 + tid];
    __syncthreads();
    float acc0 = 0.f, acc1 = 0.f;
    for (int t = 0; t < 256; ++t) {
        float av = arow[t];
        acc0 = fmaf(av, pwx[((size_t)b*256 + t)*512 + tid], acc0);
        acc1 = fmaf(av, pwx[((size_t)b*256 + t)*512 + tid + 256], acc1);
    }
    bool ok = (r < nm);
    aggm[((size_t)b*4 + r)*512 + tid]       = ok ? acc0 : 0.f;
    aggm[((size_t)b*4 + r)*512 + tid + 256] = ok ? acc1 : 0.f;
}

// ---------------- graph_mask (col-sliced) ----------------
__global__ __launch_bounds__(256)
void gmaskn_k(const float* __restrict__ aggm, const float* __restrict__ gcw,
              const float* __restrict__ gcb, const int* __restrict__ meta,
              const float* __restrict__ denom, float* __restrict__ gmsk)
{
    int b = blockIdx.x >> 1, hf = blockIdx.x & 1;
    int col = hf*256 + threadIdx.x;
    int a0 = meta[b], nm = meta[64+b];
    __shared__ float rows[4][512];
    int tid = threadIdx.x;
    #pragma unroll
    for (int r = 0; r < 4; ++r) {
        rows[r][tid]       = aggm[((size_t)b*4 + r)*512 + tid];
        rows[r][tid + 256] = aggm[((size_t)b*4 + r)*512 + tid + 256];
    }
    float inv[4];
    #pragma unroll
    for (int r = 0; r < 4; ++r) {
        int srow = a0 + r; if (srow > 255) srow = 255;
        inv[r] = 1.f / denom[b*256 + srow];
    }
    __syncthreads();
    float gm[4] = {0.f, 0.f, 0.f, 0.f};
    for (int k = 1; k <= 5; ++k) {
        const float* w = gcw + (size_t)k*262144 + col;
        float bb = gcb[k*512 + col];
        float ak[4] = {0.f, 0.f, 0.f, 0.f};
        for (int c = 0; c < 512; ++c) {
            float wv = w[(size_t)c*512];
            #pragma unroll
            for (int r = 0; r < 4; ++r) ak[r] = fmaf(rows[r][c], wv, ak[r]);
        }
        #pragma unroll
        for (int r = 0; r < 4; ++r) gm[r] += fmaxf(fmaf(ak[r], inv[r], bb), 0.f);
    }
    #pragma unroll
    for (int r = 0; r < 4; ++r)
        gmsk[((size_t)b*4 + r)*512 + col] = (r < nm) ? gm[r] : 0.f;
}

// ---------------- conv1 (col-sliced) ----------------
__global__ __launch_bounds__(256)
void conv1n_k(const float* __restrict__ pwt, const float* __restrict__ w1T,
              const float* __restrict__ b1, const int* __restrict__ meta,
              const float* __restrict__ posw, float* __restrict__ c1pw)
{
    int b = blockIdx.x >> 1, hf = blockIdx.x & 1;
    int col = hf*256 + threadIdx.x;
    int a0 = meta[b];
    __shared__ float rows[8][512];
    int tid = threadIdx.x;
    #pragma unroll
    for (int i = 0; i < 8; ++i) {
        int si = a0 - 2 + i;
        bool v = (si >= 0 && si < 256);
        rows[i][tid]       = v ? pwt[((size_t)b*256 + si)*512 + tid]       : 0.f;
        rows[i][tid + 256] = v ? pwt[((size_t)b*256 + si)*512 + tid + 256] : 0.f;
    }
    __syncthreads();
    float bv = b1[col];
    float acc[6] = {bv, bv, bv, bv, bv, bv};
    #pragma unroll
    for (int kk = 0; kk < 3; ++kk) {
        const float* w = w1T + (size_t)kk*262144 + col;
        for (int c = 0; c < 512; ++c) {
            float wv = w[(size_t)c*512];
            #pragma unroll
            for (int r = 0; r < 6; ++r) acc[r] = fmaf(rows[r + kk][c], wv, acc[r]);
        }
    }
    #pragma unroll
    for (int r = 0; r < 6; ++r) {
        int s = a0 - 1 + r;
        bool valid = (s >= 0 && s < 256);
        float pv = valid ? posw[b*256 + s] : 0.f;
        c1pw[((size_t)b*6 + r)*512 + col] = valid ? fmaxf(acc[r], 0.f)*pv : 0.f;
    }
}

// ---------------- conv2 (col-sliced) ----------------
__global__ __launch_bounds__(256)
void conv2n_k(const float* __restrict__ c1pw, const float* __restrict__ w2T,
              const float* __restrict__ b2, const int* __restrict__ meta,
              float* __restrict__ xc2)
{
    int b = blockIdx.x >> 1, hf = blockIdx.x & 1;
    int col = hf*256 + threadIdx.x;
    int nm = meta[64+b];
    __shared__ float rows[6][512];
    int tid = threadIdx.x;
    #pragma unroll
    for (int i = 0; i < 6; ++i) {
        rows[i][tid]       = c1pw[((size_t)b*6 + i)*512 + tid];
        rows[i][tid + 256] = c1pw[((size_t)b*6 + i)*512 + tid + 256];
    }
    __syncthreads();
    float bv = b2[col];
    float acc[4] = {bv, bv, bv, bv};
    #pragma unroll
    for (int kk = 0; kk < 3; ++kk) {
        const float* w = w2T + (size_t)kk*262144 + col;
        for (int c = 0; c < 512; ++c) {
            float wv = w[(size_t)c*512];
            #pragma unroll
            for (int r = 0; r < 4; ++r) acc[r] = fmaf(rows[r + kk][c], wv, acc[r]);
        }
    }
    #pragma unroll
    for (int r = 0; r < 4; ++r)
        xc2[((size_t)b*4 + r)*512 + col] = (r < nm) ? fmaxf(acc[r], 0.f) : 0.f;
}

// ---------------- multi-hop attend, 1024 threads ----------------
__global__ __launch_bounds__(1024)
void attend_k(const float* __restrict__ text_out, const float* __restrict__ tOutT,
              const float* __restrict__ gmsk, const float* __restrict__ xc2,
              const int* __restrict__ meta,
              const float* __restrict__ lng, const float* __restrict__ lnb,
              float* __restrict__ avec)
{
    __shared__ float m5[5][512];
    __shared__ float alpha[5][256];
    __shared__ float part[5120];
    __shared__ float wt[256];
    __shared__ float msum[512];
    __shared__ float red[16];
    int b = blockIdx.x, att = blockIdx.y;
    int tid = threadIdx.x;
    int a0 = meta[b], nm = meta[64+b];
    float lgam = 0.f, lbet = 0.f;
    if (tid < 512) {
        #pragma unroll
        for (int r = 0; r < 4; ++r) {
            float v = 0.f;
            if (r < nm) {
                if (att == 0)      v = gmsk[((size_t)b*4 + r)*512 + tid];
                else if (att == 1) v = text_out[((size_t)b*256 + a0 + r)*512 + tid];
                else               v = xc2[((size_t)b*4 + r)*512 + tid];
            }
            m5[r][tid] = v;
        }
        m5[4][tid] = 0.f;
        lgam = lng[att*512 + tid]; lbet = lnb[att*512 + tid];
    }
    const float* tT = tOutT + (size_t)b*512*256;
    const float* tO = text_out + (size_t)b*256*512;
    __syncthreads();

    for (int hop = 0; hop < 9; ++hop) {
        {
            int t = tid & 255, hq = tid >> 8;
            float a5[5] = {0.f, 0.f, 0.f, 0.f, 0.f};
            const float* tp = tT + (size_t)(hq*128)*256 + t;
            for (int h = 0; h < 128; ++h) {
                float v = tp[(size_t)h*256];
                int hh = hq*128 + h;
                #pragma unroll
                for (int r = 0; r < 5; ++r) a5[r] = fmaf(m5[r][hh], v, a5[r]);
            }
            #pragma unroll
            for (int r = 0; r < 5; ++r) part[(hq*5 + r)*256 + t] = a5[r];
        }
        __syncthreads();
        for (int idx = tid; idx < 1280; idx += 1024) {
            int r = idx >> 8, t2 = idx & 255;
            alpha[r][t2] = part[(0*5+r)*256+t2] + part[(1*5+r)*256+t2]
                         + part[(2*5+r)*256+t2] + part[(3*5+r)*256+t2];
        }
        __syncthreads();
        {
            int hh = tid & 511, hf2 = tid >> 9;
            float a5[5] = {0.f, 0.f, 0.f, 0.f, 0.f};
            const float* tp0 = tO + (size_t)(hf2*128)*512 + hh;
            for (int t = 0; t < 128; ++t) {
                float v = tp0[(size_t)t*512];
                #pragma unroll
                for (int r = 0; r < 5; ++r) a5[r] = fmaf(alpha[r][hf2*128 + t], v, a5[r]);
            }
            #pragma unroll
            for (int r = 0; r < 5; ++r) part[(hf2*5 + r)*512 + hh] = a5[r];
        }
        __syncthreads();
        #pragma unroll 1
        for (int r = 0; r < 5; ++r) {
            bool act = tid < 512;
            float xv = 0.f;
            if (act) xv = sigf(part[(0*5+r)*512 + tid] + part[(1*5+r)*512 + tid]);
            float s1 = act ? xv : 0.f;
            #pragma unroll
            for (int off = 1; off < 64; off <<= 1) s1 += __shfl_xor(s1, off);
            if ((tid & 63) == 0) red[tid >> 6] = s1;
            __syncthreads();
            float mu = (red[0]+red[1]+red[2]+red[3]+red[4]+red[5]+red[6]+red[7]) * (1.f/512.f);
            __syncthreads();
            float d = xv - mu;
            float s2 = act ? d*d : 0.f;
            #pragma unroll
            for (int off = 1; off < 64; off <<= 1) s2 += __shfl_xor(s2, off);
            if ((tid & 63) == 0) red[tid >> 6] = s2;
            __syncthreads();
            float var = (red[0]+red[1]+red[2]+red[3]+red[4]+red[5]+red[6]+red[7]) * (1.f/512.f);
            __syncthreads();
            if (act) {
                float ln = d * rsqrtf(var + 1e-12f) * lgam + lbet;
                if (r < nm || r == 4) m5[r][tid] += 0.01f * ln;
            }
        }
        __syncthreads();
    }
    if (tid < 512) {
        float ms = 0.f;
        #pragma unroll
        for (int r = 0; r < 4; ++r) if (r < nm) ms += m5[r][tid];
        ms += (float)(256 - nm) * m5[4][tid];
        msum[tid] = ms;
    }
    __syncthreads();
    {
        int t = tid & 255, hq = tid >> 8;
        float sc = 0.f;
        const float* tp = tT + (size_t)(hq*128)*256 + t;
        for (int h = 0; h < 128; ++h) sc = fmaf(msum[hq*128 + h], tp[(size_t)h*256], sc);
        part[hq*256 + t] = sc;
    }
    __syncthreads();
    float sv = -3.0e38f;
    if (tid < 256) sv = part[tid] + part[256+tid] + part[512+tid] + part[768+tid];
    float mx = sv;
    #pragma unroll
    for (int off = 1; off < 64; off <<= 1) mx = fmaxf(mx, __shfl_xor(mx, off));
    if ((tid & 63) == 0) red[tid >> 6] = mx;
    __syncthreads();
    mx = fmaxf(fmaxf(red[0], red[1]), fmaxf(red[2], red[3]));
    __syncthreads();
    float ex = (tid < 256) ? expf(sv - mx) : 0.f;
    float ss = ex;
    #pragma unroll
    for (int off = 1; off < 64; off <<= 1) ss += __shfl_xor(ss, off);
    if ((tid & 63) == 0) red[tid >> 6] = ss;
    __syncthreads();
    float tot = red[0]+red[1]+red[2]+red[3];
    __syncthreads();
    if (tid < 256) wt[tid] = ex / tot;
    __syncthreads();
    {
        int hh = tid & 511, hf2 = tid >> 9;
        float acc = 0.f;
        const float* tp0 = tO + (size_t)(hf2*128)*512 + hh;
        for (int t = 0; t < 128; ++t) acc = fmaf(wt[hf2*128 + t], tp0[(size_t)t*512], acc);
        part[hf2*512 + hh] = acc;
    }
    __syncthreads();
    if (tid < 512)
        avec[((size_t)att*32 + b)*512 + tid] = part[tid] + part[512 + tid];
}

// ---------------- final FC ----------------
__global__ __launch_bounds__(128)
void final_k(const float* __restrict__ avec, const float* __restrict__ fw,
             const float* __restrict__ fbb, float* __restrict__ out)
{
    int b = blockIdx.x, tid = threadIdx.x;
    float a0 = 0.f, a1 = 0.f, a2 = 0.f;
    for (int j = tid; j < 1536; j += 128) {
        float v = avec[((size_t)(j >> 9)*32 + b)*512 + (j & 511)];
        a0 = fmaf(v, fw[j], a0);
        a1 = fmaf(v, fw[1536 + j], a1);
        a2 = fmaf(v, fw[3072 + j], a2);
    }
    #pragma unroll
    for (int off = 1; off < 64; off <<= 1) {
        a0 += __shfl_xor(a0, off); a1 += __shfl_xor(a1, off); a2 += __shfl_xor(a2, off);
    }
    __shared__ float red[6];
    if ((tid & 63) == 0) { int w = tid >> 6; red[w] = a0; red[2+w] = a1; red[4+w] = a2; }
    __syncthreads();
    if (tid == 0) {
        out[b*3+0] = red[0] + red[1] + fbb[0];
        out[b*3+1] = red[2] + red[3] + fbb[1];
        out[b*3+2] = red[4] + red[5] + fbb[2];
    }
}

extern "C" void kernel_launch(void* const* d_in, const int* in_sizes, int n_in,
                              void* d_out, int out_size, void* d_ws, size_t ws_size,
                              hipStream_t stream)
{
    (void)in_sizes; (void)n_in; (void)out_size;
    if (ws_size < WS_NEED) return;
    const int*   ti    = (const int*)d_in[0];
    const int*   ai    = (const int*)d_in[1];
    const int*   li    = (const int*)d_in[2];
    const float* adj   = (const float*)d_in[3];
    const float* emb   = (const float*)d_in[4];
    const float* wih_f = (const float*)d_in[5];
    const float* whh_f = (const float*)d_in[6];
    const float* b_f   = (const float*)d_in[7];
    const float* wih_b = (const float*)d_in[8];
    const float* whh_b = (const float*)d_in[9];
    const float* b_b   = (const float*)d_in[10];
    const float* gcw   = (const float*)d_in[11];
    const float* gcb   = (const float*)d_in[12];
    const float* c1w   = (const float*)d_in[13];
    const float* c1b   = (const float*)d_in[14];
    const float* c2w   = (const float*)d_in[15];
    const float* c2b   = (const float*)d_in[16];
    const float* fw    = (const float*)d_in[17];
    const float* fb    = (const float*)d_in[18];
    const float* lng   = (const float*)d_in[19];
    const float* lnb   = (const float*)d_in[20];

    char* ws = (char*)d_ws;
    __half* X2h      = (__half*)(ws + OFF_X2);
    __half* pre      = (__half*)(ws + OFF_PRE);
    u32*    mb       = (u32*)(ws + OFF_MB);
    u32*    flags    = (u32*)(ws + OFF_FLG);
    float*  text_out = (float*)(ws + OFF_TOUT);
    float*  tOutT    = (float*)(ws + OFF_TOUTT);
    float*  pw_text  = (float*)(ws + OFF_PWT);
    u32*    pwtThi   = (u32*)(ws + OFF_PWTTH);
    u32*    pwtTlo   = (u32*)(ws + OFF_PWTTL);
    float*  y        = (float*)(ws + OFF_Y);
    float*  agg0     = (float*)(ws + OFF_AGG0);
    u32*    Ghi      = (u32*)(ws + OFF_GCWT);
    u32*    Glo      = (u32*)(ws + OFF_GCWT + 524288);
    float*  pwx      = (float*)(ws + OFF_PWX);
    u64*    Hs       = (u64*)(ws + OFF_PWX);   // scan-time overlay
    u32*    Wmf      = (u32*)(ws + OFF_WD);
    u32*    Wih      = (u32*)(ws + OFF_WIH);
    float*  biascat  = (float*)(ws + OFF_BIA);
    float*  w1T      = (float*)(ws + OFF_W1T);
    float*  w2T      = (float*)(ws + OFF_W2T);
    int*    meta     = (int*)(ws + OFF_META);
    float*  clf      = (float*)(ws + OFF_CLF);
    float*  denom    = (float*)(ws + OFF_DEN);
    float*  posw     = (float*)(ws + OFF_POSW);
    float*  aggm     = (float*)(ws + OFF_AGGM);
    float*  gmsk     = (float*)(ws + OFF_GMSK);
    float*  c1pw     = (float*)(ws + OFF_C1PW);
    float*  xc2      = (float*)(ws + OFF_XC2);
    float*  avec     = (float*)(ws + OFF_AVEC);

    len_k<<<1, 64, 0, stream>>>(ti, ai, li, meta, clf);
    pd_k<<<8192, 256, 0, stream>>>(adj, meta, clf, denom, posw);
    gather_k<<<8192, 128, 0, stream>>>(ti, emb, X2h);
    wpackih_k<<<2560, 256, 0, stream>>>(wih_f, wih_b, Wih);
    wmf_k<<<4096, 256, 0, stream>>>(whh_f, whh_b, Wmf);
    wtrans_k<<<dim3(3072, 2), 256, 0, stream>>>(c1w, c2w, w1T, w2T);
    hipMemcpyAsync(biascat,        b_f, 2048*4, hipMemcpyDeviceToDevice, stream);
    hipMemcpyAsync(biascat + 2048, b_b, 2048*4, hipMemcpyDeviceToDevice, stream);

    pre_mfma_k<<<dim3(64, 32), 256, 0, stream>>>((const u32*)X2h, Wih, biascat, pre);

    maskb_k<<<1, 256, 0, stream>>>(ti, mb);
    hipMemsetAsync(flags, 0, (size_t)257*128*4, stream);

    lstm_scan7_k<<<64, 256, 0, stream>>>(pre, Wmf, mb, y, flags, Hs);

    fuse_ct_k<<<dim3(8, 16, 32), 256, 0, stream>>>(y, posw, text_out, pw_text,
                                                   tOutT, pwtThi, pwtTlo);
    mmsplit_k<0, 0><<<dim3(2, 4, 32), 256, 0, stream>>>(adj, pwtThi, pwtTlo, agg0,
        512, 128, 65536L, 65536L, 131072L, nullptr, nullptr, nullptr);
    wpackg_k<<<512, 256, 0, stream>>>(gcw, Ghi, Glo);
    mmsplit_k<1, 1><<<dim3(64, 4, 1), 256, 0, stream>>>(agg0, Ghi, Glo, pwx,
        512, 256, 0L, 0L, 0L, gcb, denom, posw);

    aggm_k<<<128, 256, 0, stream>>>(adj, pwx, meta, aggm);
    gmaskn_k<<<64, 256, 0, stream>>>(aggm, gcw, gcb, meta, denom, gmsk);
    conv1n_k<<<64, 256, 0, stream>>>(pw_text, w1T, c1b, meta, posw, c1pw);
    conv2n_k<<<64, 256, 0, stream>>>(c1pw, w2T, c2b, meta, xc2);
    attend_k<<<dim3(32, 3), 1024, 0, stream>>>(text_out, tOutT, gmsk, xc2, meta, lng, lnb, avec);
    final_k<<<32, 128, 0, stream>>>(avec, fw, fb, (float*)d_out);
}

// Round 10
// 1493.953 us; speedup vs baseline: 1.6516x; 1.6516x over previous
//
#include <hip/hip_runtime.h>
#include <hip/hip_fp16.h>

typedef unsigned int u32;
typedef unsigned long long u64;

// ---------------- workspace layout (bytes) ----------------
static constexpr size_t OFF_X2    = 0;          // X2h [8192][320] f16 (dead after pre-gemm)
static constexpr size_t OFF_PRE   = 9830400;    // pre [8192][4096] f16 (dead after scan)
// scan-time overlays inside X2 region (X2h dead by then):
static constexpr size_t OFF_MB    = 131072;     // mask bits [256] u32
static constexpr size_t OFF_FLG   = 135168;     // flags [257][128] u32 = 131584 B
// post-scan overlays:
static constexpr size_t OFF_TOUT  = 0;          // text_out [32][256][512] f32
static constexpr size_t OFF_TOUTT = 16777216;   // tOutT    [32][512][256] f32
static constexpr size_t OFF_PWT   = 33554432;   // pw_text  [32][256][512] f32
static constexpr size_t OFF_PWTTH = 50331648;   // pwtT_hi [32][512][256] f16 = 8MB
static constexpr size_t OFF_PWTTL = 58720256;   // pwtT_lo [32][512][256] f16 = 8MB
static constexpr size_t OFF_Y     = 76939264;   // y [2][32][256][512] f32 (dead after fuse_ct)
static constexpr size_t OFF_AGG0  = 76939264;   // agg0 f32 (overlays dead y)
static constexpr size_t OFF_GCWT  = 93716480;   // gcw0T hi/lo (overlays dead y)
static constexpr size_t OFF_PWX   = 110493696;  // pwx f32; during scan: Hs[256][2][32][128]u64 = 16MB
static constexpr size_t OFF_WD    = 127270912;  // Wmf packed fp16 whh A-frags = 4MB
static constexpr size_t OFF_WIH   = 131465216;  // wihh [4096][320] f16
static constexpr size_t OFF_BIA   = 136380416;  // biascat [4096] f32
static constexpr size_t OFF_W1T   = 136396800;  // w1T [3][512][512] f32
static constexpr size_t OFF_W2T   = 139542528;  // w2T [3][512][512] f32
static constexpr size_t OFF_META  = 142688256;  // int a0[32],a1[32],nm[32],tl[32]
static constexpr size_t OFF_CLF   = 142688768;  // float cl[32]
static constexpr size_t OFF_DEN   = 142688896;  // denom [32][256] f32
static constexpr size_t OFF_POSW  = 142721664;  // posw  [32][256] f32
static constexpr size_t OFF_AGGM  = 142754432;  // aggm [32][4][512] f32
static constexpr size_t OFF_GMSK  = 143016576;  // gmask [32][4][512] f32
static constexpr size_t OFF_C1PW  = 143278720;  // c1pw [32][6][512] f32
static constexpr size_t OFF_XC2   = 143671936;  // xc2 [32][4][512] f32
static constexpr size_t OFF_AVEC  = 143934080;  // avec [3][32][512] f32
static constexpr size_t WS_NEED   = 144130688;

__device__ __forceinline__ float sigf(float x) { return 1.f / (1.f + expf(-x)); }

typedef _Float16 half8 __attribute__((ext_vector_type(8)));
typedef float f32x4 __attribute__((ext_vector_type(4)));
union U4H8 { uint4 u; half8 h; };

__device__ __forceinline__ u32 packh2(float a, float b) {
    return (u32)__half_as_ushort(__float2half(a)) |
           ((u32)__half_as_ushort(__float2half(b)) << 16);
}

// ---------------- lengths / meta ----------------
__global__ void len_k(const int* __restrict__ ti, const int* __restrict__ ai,
                      const int* __restrict__ li, int* __restrict__ meta, float* __restrict__ clf)
{
    int b = threadIdx.x;
    if (b >= 32) return;
    int tl = 0;
    for (int s = 0; s < 256; ++s) tl += (ti[b*256+s] != 0);
    int al = 0;
    for (int i = 0; i < 4; ++i) al += (ai[b*4+i] != 0);
    int ll = 0;
    for (int i = 0; i < 16; ++i) ll += (li[b*16+i] != 0);
    meta[b]      = ll;
    meta[32+b]   = ll + al - 1;
    meta[64+b]   = al;
    meta[96+b]   = tl;
    clf[b] = (float)(tl - al);
}

// ---------------- denom + pos-weight ----------------
__global__ __launch_bounds__(256)
void pd_k(const float* __restrict__ adj, const int* __restrict__ meta,
          const float* __restrict__ clf, float* __restrict__ denom, float* __restrict__ posw)
{
    int row = blockIdx.x;            // b*256+s
    int b = row >> 8, s = row & 255;
    int tid = threadIdx.x;
    float v = adj[(size_t)row*256 + tid];
    #pragma unroll
    for (int off = 1; off < 64; off <<= 1) v += __shfl_xor(v, off);
    __shared__ float rd[4];
    if ((tid & 63) == 0) rd[tid >> 6] = v;
    __syncthreads();
    if (tid == 0) {
        denom[row] = rd[0] + rd[1] + rd[2] + rd[3] + 1.f;
        int a0 = meta[b], a1 = meta[32+b], tl = meta[96+b];
        float cl = clf[b];
        float w;
        if (s < a0)       w = 1.f - (float)(a0 - s) / cl;
        else if (s <= a1) w = 0.f;
        else if (s < tl)  w = 1.f - (float)(s - a1) / cl;
        else              w = 0.f;
        posw[row] = w;
    }
}

// ---------------- embedding gather ----------------
__global__ __launch_bounds__(128)
void gather_k(const int* __restrict__ ti, const float* __restrict__ emb, __half* __restrict__ X2h)
{
    int row = blockIdx.x;            // s*32+b
    int b = row & 31, s = row >> 5;
    int idx = ti[b*256 + s];
    const float* e = emb + (size_t)idx*300;
    __half* o = X2h + (size_t)row*320;
    for (int k = threadIdx.x; k < 320; k += 128)
        o[k] = (k < 300) ? __float2half(e[k]) : __ushort_as_half((unsigned short)0);
}

// ---------------- pack wih -> f16 rows ----------------
__global__ __launch_bounds__(256)
void wpackih_k(const float* __restrict__ wf, const float* __restrict__ wb, u32* __restrict__ Wih)
{
    u32 idx = blockIdx.x*256 + threadIdx.x;
    if (idx >= 655360u) return;
    int n = idx / 160;
    int j = idx - n*160;
    int k0 = 2*j;
    const float* w = (n < 2048) ? (wf + (size_t)n*300) : (wb + (size_t)(n - 2048)*300);
    float v0 = (k0   < 300) ? w[k0]   : 0.f;
    float v1 = (k0+1 < 300) ? w[k0+1] : 0.f;
    Wih[idx] = packh2(v0, v1);
}

// ---------------- pack whh -> MFMA A-fragment layout ----------------
__global__ __launch_bounds__(256)
void wmf_k(const float* __restrict__ wf, const float* __restrict__ wb, u32* __restrict__ Wmf)
{
    u32 idx = blockIdx.x*256 + threadIdx.x;   // < 1,048,576
    int e2 = idx & 3;
    int l  = (idx >> 2) & 63;
    int c  = (idx >> 8) & 3;
    int mt = (idx >> 10) & 1;
    int wv = (idx >> 11) & 3;
    int g  = (idx >> 13) & 63;
    int dir = (int)(idx >> 19);
    int kloc = wv*128 + c*32 + 16*(e2 >> 1) + 4*(l >> 4) + 2*(e2 & 1);
    int ml = mt*16 + (l & 15);
    int n = (ml & 3)*512 + g*8 + (ml >> 2);
    const float* w = dir ? wb : wf;
    Wmf[idx] = packh2(w[(size_t)n*512 + kloc], w[(size_t)n*512 + kloc + 1]);
}

// ---------------- mask bits ----------------
__global__ void maskb_k(const int* __restrict__ ti, u32* __restrict__ mb)
{
    int s = threadIdx.x;
    u32 w = 0;
    for (int b = 0; b < 32; ++b) w |= (u32)(ti[b*256 + s] != 0) << b;
    mb[s] = w;
}

// ---------------- conv weight transpose ----------------
__global__ __launch_bounds__(256)
void wtrans_k(const float* __restrict__ w1, const float* __restrict__ w2,
              float* __restrict__ w1T, float* __restrict__ w2T)
{
    u32 idx = blockIdx.x*256 + threadIdx.x;
    const float* src = blockIdx.y ? w2 : w1;
    float* dst = blockIdx.y ? w2T : w1T;
    int k = idx >> 18;
    int i = (idx >> 9) & 511;
    int o = idx & 511;
    dst[idx] = src[((size_t)o*512 + i)*3 + k];
}

// ---------------- pack gcw[0]^T -> f16 hi/lo ----------------
__global__ __launch_bounds__(256)
void wpackg_k(const float* __restrict__ gcw, u32* __restrict__ Ghi, u32* __restrict__ Glo)
{
    u32 idx = blockIdx.x*256 + threadIdx.x;   // < 131072
    int n = idx >> 8, k2 = idx & 255;
    float v0 = gcw[(size_t)(2*k2)*512 + n];
    float v1 = gcw[(size_t)(2*k2 + 1)*512 + n];
    __half h0 = __float2half(v0), h1 = __float2half(v1);
    Ghi[idx] = (u32)__half_as_ushort(h0) | ((u32)__half_as_ushort(h1) << 16);
    Glo[idx] = packh2(v0 - __half2float(h0), v1 - __half2float(h1));
}

// ---------------- MFMA pre-activation GEMM ----------------
__global__ __launch_bounds__(256)
void pre_mfma_k(const u32* __restrict__ X2u, const u32* __restrict__ Wihu,
                const float* __restrict__ bias, __half* __restrict__ pre)
{
    __shared__ u32 As2[16*132];
    __shared__ u32 Bs2[16*132];
    const int tid = threadIdx.x;
    const int wv = tid >> 6;
    const int l  = tid & 63;
    const int q  = l >> 4;
    const int l15 = l & 15;
    const int wm = wv & 1, wn = wv >> 1;
    const int m0 = blockIdx.x * 128;
    const int n0 = blockIdx.y * 128;

    f32x4 acc[4][4];
    #pragma unroll
    for (int mt = 0; mt < 4; ++mt)
        #pragma unroll
        for (int nt = 0; nt < 4; ++nt)
            acc[mt][nt] = (f32x4){0.f, 0.f, 0.f, 0.f};

    const int srow = tid >> 4;
    const int sj   = tid & 15;

    for (int kb = 0; kb < 10; ++kb) {
        #pragma unroll
        for (int i = 0; i < 8; ++i) {
            int row = srow + i*16;
            As2[sj*132 + row] = X2u[(size_t)(m0 + row)*160 + kb*16 + sj];
            Bs2[sj*132 + row] = Wihu[(size_t)(n0 + row)*160 + kb*16 + sj];
        }
        __syncthreads();

        U4H8 bf[4];
        #pragma unroll
        for (int nt = 0; nt < 4; ++nt) {
            int col = wn*64 + nt*16 + l15;
            bf[nt].u = make_uint4(Bs2[(2*q)*132 + col], Bs2[(2*q+1)*132 + col],
                                  Bs2[(2*q+8)*132 + col], Bs2[(2*q+9)*132 + col]);
        }
        #pragma unroll
        for (int mt = 0; mt < 4; ++mt) {
            int row = wm*64 + mt*16 + l15;
            U4H8 af;
            af.u = make_uint4(As2[(2*q)*132 + row], As2[(2*q+1)*132 + row],
                              As2[(2*q+8)*132 + row], As2[(2*q+9)*132 + row]);
            #pragma unroll
            for (int nt = 0; nt < 4; ++nt)
                acc[mt][nt] = __builtin_amdgcn_mfma_f32_16x16x32_f16(af.h, bf[nt].h, acc[mt][nt], 0, 0, 0);
        }
        __syncthreads();
    }

    #pragma unroll
    for (int nt = 0; nt < 4; ++nt) {
        int col = n0 + wn*64 + nt*16 + l15;
        float bv = bias[col];
        #pragma unroll
        for (int mt = 0; mt < 4; ++mt) {
            int rbase = m0 + wm*64 + mt*16 + q*4;
            #pragma unroll
            for (int p = 0; p < 4; ++p)
                pre[(size_t)(rbase + p)*4096 + col] = __float2half(acc[mt][nt][p] + bv);
        }
    }
}

// ---------------- generic hi/lo-split MFMA GEMM ----------------
template<int SPLITA, int EPI>
__global__ __launch_bounds__(256)
void mmsplit_k(const float* __restrict__ A, const u32* __restrict__ Bhi,
               const u32* __restrict__ Blo, float* __restrict__ C,
               int N, int Ku32, long sA, long sB, long sC,
               const float* __restrict__ bias, const float* __restrict__ denom,
               const float* __restrict__ posw)
{
    __shared__ u32 Ah[16*132];
    __shared__ u32 Al[16*132];
    __shared__ u32 Bh[16*132];
    __shared__ u32 Bl[16*132];
    const int z = blockIdx.z;
    A   += (size_t)z * sA;
    Bhi += (size_t)z * sB;
    Blo += (size_t)z * sB;
    C   += (size_t)z * sC;
    const int m0 = blockIdx.x * 128;
    const int n0 = blockIdx.y * 128;
    const int tid = threadIdx.x;
    const int wv = tid >> 6;
    const int l  = tid & 63;
    const int q  = l >> 4;
    const int l15 = l & 15;
    const int wm = wv & 1, wn = wv >> 1;
    const int pitchA = 2*Ku32;

    f32x4 acc[4][4];
    #pragma unroll
    for (int mt = 0; mt < 4; ++mt)
        #pragma unroll
        for (int nt = 0; nt < 4; ++nt)
            acc[mt][nt] = (f32x4){0.f, 0.f, 0.f, 0.f};

    const int srow = tid >> 4;
    const int sj   = tid & 15;
    const int nkb = Ku32 >> 4;

    for (int kb = 0; kb < nkb; ++kb) {
        #pragma unroll
        for (int i = 0; i < 8; ++i) {
            int row = srow + i*16;
            float2 av = *(const float2*)(A + (size_t)(m0 + row)*pitchA + kb*32 + 2*sj);
            __half h0 = __float2half(av.x), h1 = __float2half(av.y);
            Ah[sj*132 + row] = (u32)__half_as_ushort(h0) | ((u32)__half_as_ushort(h1) << 16);
            if (SPLITA)
                Al[sj*132 + row] = packh2(av.x - __half2float(h0), av.y - __half2float(h1));
            Bh[sj*132 + row] = Bhi[(size_t)(n0 + row)*Ku32 + kb*16 + sj];
            Bl[sj*132 + row] = Blo[(size_t)(n0 + row)*Ku32 + kb*16 + sj];
        }
        __syncthreads();

        U4H8 bfh[4], bfl[4];
        #pragma unroll
        for (int nt = 0; nt < 4; ++nt) {
            int col = wn*64 + nt*16 + l15;
            bfh[nt].u = make_uint4(Bh[(2*q)*132 + col], Bh[(2*q+1)*132 + col],
                                   Bh[(2*q+8)*132 + col], Bh[(2*q+9)*132 + col]);
            bfl[nt].u = make_uint4(Bl[(2*q)*132 + col], Bl[(2*q+1)*132 + col],
                                   Bl[(2*q+8)*132 + col], Bl[(2*q+9)*132 + col]);
        }
        #pragma unroll
        for (int mt = 0; mt < 4; ++mt) {
            int row = wm*64 + mt*16 + l15;
            U4H8 afh;
            afh.u = make_uint4(Ah[(2*q)*132 + row], Ah[(2*q+1)*132 + row],
                               Ah[(2*q+8)*132 + row], Ah[(2*q+9)*132 + row]);
            #pragma unroll
            for (int nt = 0; nt < 4; ++nt) {
                acc[mt][nt] = __builtin_amdgcn_mfma_f32_16x16x32_f16(afh.h, bfh[nt].h, acc[mt][nt], 0, 0, 0);
                acc[mt][nt] = __builtin_amdgcn_mfma_f32_16x16x32_f16(afh.h, bfl[nt].h, acc[mt][nt], 0, 0, 0);
            }
            if (SPLITA) {
                U4H8 afl;
                afl.u = make_uint4(Al[(2*q)*132 + row], Al[(2*q+1)*132 + row],
                                   Al[(2*q+8)*132 + row], Al[(2*q+9)*132 + row]);
                #pragma unroll
                for (int nt = 0; nt < 4; ++nt)
                    acc[mt][nt] = __builtin_amdgcn_mfma_f32_16x16x32_f16(afl.h, bfh[nt].h, acc[mt][nt], 0, 0, 0);
            }
        }
        __syncthreads();
    }

    #pragma unroll
    for (int nt = 0; nt < 4; ++nt) {
        int col = n0 + wn*64 + nt*16 + l15;
        float bv = (EPI == 1) ? bias[col] : 0.f;
        #pragma unroll
        for (int mt = 0; mt < 4; ++mt) {
            int rbase = m0 + wm*64 + mt*16 + q*4;
            #pragma unroll
            for (int p = 0; p < 4; ++p) {
                int m = rbase + p;
                if (EPI == 0) {
                    C[(size_t)m*N + col] = acc[mt][nt][p];
                } else {
                    float v = fmaf(acc[mt][nt][p], 1.f/denom[m], bv);
                    C[(size_t)m*N + col] = fmaxf(v, 0.f) * posw[m];
                }
            }
        }
    }
}

// ---------------- persistent batched LSTM scan (v6 + RMW poll) ----------------
__global__ __launch_bounds__(256, 1)
void lstm_scan6_k(const __half* __restrict__ pre, const u32* __restrict__ Wmf,
                  const u32* __restrict__ mb, float* __restrict__ y,
                  u32* __restrict__ flags, u64* __restrict__ Hs)
{
    __shared__ u32 hs[32*264];
    __shared__ float gred[4352];

    const int tid = threadIdx.x;
    const int wv = tid >> 6;
    const int l  = tid & 63;
    const int q  = l >> 4;
    const int l15 = l & 15;
    const int dir = blockIdx.x & 1;
    const int g   = blockIdx.x >> 1;
    const int b2 = tid >> 3;
    const int jj = tid & 7;
    const int gcol = g*8 + jj;

    half8 afr[2][4];
    {
        const uint4* wp = (const uint4*)(Wmf + ((((size_t)dir*64 + g)*4 + wv)*2048)) + l;
        #pragma unroll
        for (int mt = 0; mt < 2; ++mt)
            #pragma unroll
            for (int c = 0; c < 4; ++c)
                afr[mt][c] = __builtin_bit_cast(half8, wp[(mt*4 + c)*64]);
    }

    float hreg = 0.f, creg = 0.f;

    const int s0 = dir ? 255 : 0;
    __half ph[4];
    #pragma unroll
    for (int gt = 0; gt < 4; ++gt)
        ph[gt] = pre[((size_t)s0*32 + b2)*4096 + dir*2048 + gt*512 + gcol];
    u32 mbv = mb[s0];

    const int ks64 = wv*64;
    const int srow = tid >> 3, scol = tid & 7;

    for (int t = 0; t < 256; ++t) {
        const int s = dir ? (255 - t) : t;

        if (t == 0) {
            u32* dst = &hs[srow*264 + scol*4];
            #pragma unroll
            for (int i = 0; i < 8; ++i) *(uint4*)(dst + i*32) = make_uint4(0u,0u,0u,0u);
        } else {
            if (tid < 64) {
                u32* fp = flags + (size_t)t*128 + dir*64 + tid;
                int guard = 0;
                // RMW poll: never served from a stale cache line
                u32 fv = __hip_atomic_fetch_add(fp, 0u, __ATOMIC_RELAXED, __HIP_MEMORY_SCOPE_AGENT);
                while (!__all(fv != 0u)) {
                    __builtin_amdgcn_s_sleep(1);
                    fv = __hip_atomic_fetch_add(fp, 0u, __ATOMIC_RELAXED, __HIP_MEMORY_SCOPE_AGENT);
                    if (++guard > (1 << 22)) break;
                }
            }
            __syncthreads();
            int bi = (int)(__brev((u32)t) >> 24);
            const uint4* src = (const uint4*)(Hs + ((size_t)(bi*2 + dir)*32)*128);
            const uint4* tp = src + srow*64 + scol;
            uint4 vv[8];
            #pragma unroll
            for (int i = 0; i < 8; ++i) vv[i] = tp[i*8];
            u32* dst = &hs[srow*264 + scol*4];
            #pragma unroll
            for (int i = 0; i < 8; ++i) *(uint4*)(dst + i*32) = vv[i];
        }
        __syncthreads();

        f32x4 acc[2][2];
        #pragma unroll
        for (int mt = 0; mt < 2; ++mt)
            #pragma unroll
            for (int nt = 0; nt < 2; ++nt)
                acc[mt][nt] = (f32x4){0.f, 0.f, 0.f, 0.f};
        #pragma unroll
        for (int c = 0; c < 4; ++c) {
            #pragma unroll
            for (int nt = 0; nt < 2; ++nt) {
                int base = (nt*16 + l15)*264 + ks64 + c*16 + 2*q;
                uint4 bw = make_uint4(hs[base], hs[base+1], hs[base+8], hs[base+9]);
                half8 bfr = __builtin_bit_cast(half8, bw);
                acc[0][nt] = __builtin_amdgcn_mfma_f32_16x16x32_f16(afr[0][c], bfr, acc[0][nt], 0, 0, 0);
                acc[1][nt] = __builtin_amdgcn_mfma_f32_16x16x32_f16(afr[1][c], bfr, acc[1][nt], 0, 0, 0);
            }
        }

        #pragma unroll
        for (int mt = 0; mt < 2; ++mt)
            #pragma unroll
            for (int nt = 0; nt < 2; ++nt)
                #pragma unroll
                for (int p = 0; p < 4; ++p)
                    gred[(((wv*2 + mt)*2 + nt)*16 + q*4 + p)*17 + l15] = acc[mt][nt][p];
        __syncthreads();

        float gv[4];
        #pragma unroll
        for (int gt = 0; gt < 4; ++gt) {
            int ml = 4*jj + gt;
            int mt = ml >> 4, r = ml & 15;
            int ntile = b2 >> 4, n = b2 & 15;
            float sum = 0.f;
            #pragma unroll
            for (int w2 = 0; w2 < 4; ++w2)
                sum += gred[(((w2*2 + mt)*2 + ntile)*16 + r)*17 + n];
            gv[gt] = sum + __half2float(ph[gt]);
        }
        float cn = sigf(gv[1])*creg + sigf(gv[0])*tanhf(gv[2]);
        float hn = sigf(gv[3])*tanhf(cn);
        bool mk = (mbv >> b2) & 1u;
        if (mk) { hreg = hn; creg = cn; }

        {
            int l4 = l & ~3;
            float h0 = __shfl(hreg, l4 + 0);
            float h1 = __shfl(hreg, l4 + 1);
            float h2 = __shfl(hreg, l4 + 2);
            float h3 = __shfl(hreg, l4 + 3);
            if ((tid & 3) == 0) {
                u64 pk = (u64)packh2(h0, h1) | ((u64)packh2(h2, h3) << 32);
                int bi2 = (int)(__brev((u32)(t + 1)) >> 24);
                int wsel = (tid >> 2) & 1;
                __hip_atomic_store(&Hs[((size_t)(bi2*2 + dir)*32 + b2)*128 + 2*g + wsel], pk,
                                   __ATOMIC_RELAXED, __HIP_MEMORY_SCOPE_AGENT);
            }
        }
        asm volatile("s_waitcnt vmcnt(0)" ::: "memory");
        __syncthreads();
        if (tid == 0) {
            __hip_atomic_store(flags + (size_t)(t + 1)*128 + dir*64 + g, 1u,
                               __ATOMIC_RELAXED, __HIP_MEMORY_SCOPE_AGENT);
        }
        y[(((size_t)dir*32 + b2)*256 + s)*512 + gcol] = mk ? hn : 0.f;

        if (t < 255) {
            int sn = dir ? (254 - t) : (t + 1);
            #pragma unroll
            for (int gt = 0; gt < 4; ++gt)
                ph[gt] = pre[((size_t)sn*32 + b2)*4096 + dir*2048 + gt*512 + gcol];
            mbv = mb[sn];
        }
    }
}

// ---------------- fused combine + transpose + pwtT hi/lo pack ----------------
__global__ __launch_bounds__(256)
void fuse_ct_k(const float* __restrict__ y, const float* __restrict__ posw,
               float* __restrict__ text_out, float* __restrict__ pw_text,
               float* __restrict__ tOutT, u32* __restrict__ pwtThi, u32* __restrict__ pwtTlo)
{
    __shared__ float tileV[32][33];
    __shared__ float tileP[32][33];
    int b = blockIdx.z, s0 = blockIdx.x*32, h0 = blockIdx.y*32;
    int tx = threadIdx.x & 31, ty4 = threadIdx.x >> 5;
    int hg = h0 + tx;
    #pragma unroll
    for (int rr = 0; rr < 4; ++rr) {
        int sy = ty4 + rr*8;
        int s = s0 + sy;
        const float* p;
        if (hg < 256) p = y + (((size_t)b*256 + s)*512 + 2*hg);
        else          p = y + (((size_t)(32 + b)*256 + s)*512 + 2*(hg - 256));
        float v = 0.5f*(p[0] + p[1]);
        float pw = v * posw[b*256 + s];
        text_out[((size_t)b*256 + s)*512 + hg] = v;
        pw_text [((size_t)b*256 + s)*512 + hg] = pw;
        tileV[sy][tx] = v;
        tileP[sy][tx] = pw;
    }
    __syncthreads();
    #pragma unroll
    for (int rr = 0; rr < 4; ++rr) {
        int hy = ty4 + rr*8;
        tOutT[((size_t)b*512 + h0 + hy)*256 + s0 + tx] = tileV[tx][hy];
    }
    for (int slot = threadIdx.x; slot < 512; slot += 256) {
        int hh = slot >> 4, sp = slot & 15;
        float p0 = tileP[2*sp][hh];
        float p1 = tileP[2*sp + 1][hh];
        __half q0 = __float2half(p0), q1 = __float2half(p1);
        size_t di = ((size_t)b*512 + h0 + hh)*128 + (s0 >> 1) + sp;
        pwtThi[di] = (u32)__half_as_ushort(q0) | ((u32)__half_as_ushort(q1) << 16);
        pwtTlo[di] = packh2(p0 - __half2float(q0), p1 - __half2float(q1));
    }
}

// ---------------- masked-row adj aggregation ----------------
__global__ __launch_bounds__(256)
void aggm_k(const float* __restrict__ adj, const float* __restrict__ pwx,
            const int* __restrict__ meta, float* __restrict__ aggm)
{
    int b = blockIdx.x >> 2, r = blockIdx.x & 3;
    int a0 = meta[b], nm = meta[64+b];
    int s = a0 + r; if (s > 255) s = 255;
    __shared__ float arow[256];
    int tid = threadIdx.x;
    arow[tid] = adj[((size_t)b*256 + s)*256 + tid];
    __syncthreads();
    float acc0 = 0.f, acc1 = 0.f;
    for (int t = 0; t < 256; ++t) {
        float av = arow[t];
        acc0 = fmaf(av, pwx[((size_t)b*256 + t)*512 + tid], acc0);
        acc1 = fmaf(av, pwx[((size_t)b*256 + t)*512 + tid + 256], acc1);
    }
    bool ok = (r < nm);
    aggm[((size_t)b*4 + r)*512 + tid]       = ok ? acc0 : 0.f;
    aggm[((size_t)b*4 + r)*512 + tid + 256] = ok ? acc1 : 0.f;
}

// ---------------- graph_mask (col-sliced) ----------------
__global__ __launch_bounds__(256)
void gmaskn_k(const float* __restrict__ aggm, const float* __restrict__ gcw,
              const float* __restrict__ gcb, const int* __restrict__ meta,
              const float* __restrict__ denom, float* __restrict__ gmsk)
{
    int b = blockIdx.x >> 1, hf = blockIdx.x & 1;
    int col = hf*256 + threadIdx.x;
    int a0 = meta[b], nm = meta[64+b];
    __shared__ float rows[4][512];
    int tid = threadIdx.x;
    #pragma unroll
    for (int r = 0; r < 4; ++r) {
        rows[r][tid]       = aggm[((size_t)b*4 + r)*512 + tid];
        rows[r][tid + 256] = aggm[((size_t)b*4 + r)*512 + tid + 256];
    }
    float inv[4];
    #pragma unroll
    for (int r = 0; r < 4; ++r) {
        int srow = a0 + r; if (srow > 255) srow = 255;
        inv[r] = 1.f / denom[b*256 + srow];
    }
    __syncthreads();
    float gm[4] = {0.f, 0.f, 0.f, 0.f};
    for (int k = 1; k <= 5; ++k) {
        const float* w = gcw + (size_t)k*262144 + col;
        float bb = gcb[k*512 + col];
        float ak[4] = {0.f, 0.f, 0.f, 0.f};
        for (int c = 0; c < 512; ++c) {
            float wv = w[(size_t)c*512];
            #pragma unroll
            for (int r = 0; r < 4; ++r) ak[r] = fmaf(rows[r][c], wv, ak[r]);
        }
        #pragma unroll
        for (int r = 0; r < 4; ++r) gm[r] += fmaxf(fmaf(ak[r], inv[r], bb), 0.f);
    }
    #pragma unroll
    for (int r = 0; r < 4; ++r)
        gmsk[((size_t)b*4 + r)*512 + col] = (r < nm) ? gm[r] : 0.f;
}

// ---------------- conv1 (col-sliced) ----------------
__global__ __launch_bounds__(256)
void conv1n_k(const float* __restrict__ pwt, const float* __restrict__ w1T,
              const float* __restrict__ b1, const int* __restrict__ meta,
              const float* __restrict__ posw, float* __restrict__ c1pw)
{
    int b = blockIdx.x >> 1, hf = blockIdx.x & 1;
    int col = hf*256 + threadIdx.x;
    int a0 = meta[b];
    __shared__ float rows[8][512];
    int tid = threadIdx.x;
    #pragma unroll
    for (int i = 0; i < 8; ++i) {
        int si = a0 - 2 + i;
        bool v = (si >= 0 && si < 256);
        rows[i][tid]       = v ? pwt[((size_t)b*256 + si)*512 + tid]       : 0.f;
        rows[i][tid + 256] = v ? pwt[((size_t)b*256 + si)*512 + tid + 256] : 0.f;
    }
    __syncthreads();
    float bv = b1[col];
    float acc[6] = {bv, bv, bv, bv, bv, bv};
    #pragma unroll
    for (int kk = 0; kk < 3; ++kk) {
        const float* w = w1T + (size_t)kk*262144 + col;
        for (int c = 0; c < 512; ++c) {
            float wv = w[(size_t)c*512];
            #pragma unroll
            for (int r = 0; r < 6; ++r) acc[r] = fmaf(rows[r + kk][c], wv, acc[r]);
        }
    }
    #pragma unroll
    for (int r = 0; r < 6; ++r) {
        int s = a0 - 1 + r;
        bool valid = (s >= 0 && s < 256);
        float pv = valid ? posw[b*256 + s] : 0.f;
        c1pw[((size_t)b*6 + r)*512 + col] = valid ? fmaxf(acc[r], 0.f)*pv : 0.f;
    }
}

// ---------------- conv2 (col-sliced) ----------------
__global__ __launch_bounds__(256)
void conv2n_k(const float* __restrict__ c1pw, const float* __restrict__ w2T,
              const float* __restrict__ b2, const int* __restrict__ meta,
              float* __restrict__ xc2)
{
    int b = blockIdx.x >> 1, hf = blockIdx.x & 1;
    int col = hf*256 + threadIdx.x;
    int nm = meta[64+b];
    __shared__ float rows[6][512];
    int tid = threadIdx.x;
    #pragma unroll
    for (int i = 0; i < 6; ++i) {
        rows[i][tid]       = c1pw[((size_t)b*6 + i)*512 + tid];
        rows[i][tid + 256] = c1pw[((size_t)b*6 + i)*512 + tid + 256];
    }
    __syncthreads();
    float bv = b2[col];
    float acc[4] = {bv, bv, bv, bv};
    #pragma unroll
    for (int kk = 0; kk < 3; ++kk) {
        const float* w = w2T + (size_t)kk*262144 + col;
        for (int c = 0; c < 512; ++c) {
            float wv = w[(size_t)c*512];
            #pragma unroll
            for (int r = 0; r < 4; ++r) acc[r] = fmaf(rows[r + kk][c], wv, acc[r]);
        }
    }
    #pragma unroll
    for (int r = 0; r < 4; ++r)
        xc2[((size_t)b*4 + r)*512 + col] = (r < nm) ? fmaxf(acc[r], 0.f) : 0.f;
}

// ---------------- multi-hop attend, 1024 threads ----------------
__global__ __launch_bounds__(1024)
void attend_k(const float* __restrict__ text_out, const float* __restrict__ tOutT,
              const float* __restrict__ gmsk, const float* __restrict__ xc2,
              const int* __restrict__ meta,
              const float* __restrict__ lng, const float* __restrict__ lnb,
              float* __restrict__ avec)
{
    __shared__ float m5[5][512];
    __shared__ float alpha[5][256];
    __shared__ float part[5120];
    __shared__ float wt[256];
    __shared__ float msum[512];
    __shared__ float red[16];
    int b = blockIdx.x, att = blockIdx.y;
    int tid = threadIdx.x;
    int a0 = meta[b], nm = meta[64+b];
    float lgam = 0.f, lbet = 0.f;
    if (tid < 512) {
        #pragma unroll
        for (int r = 0; r < 4; ++r) {
            float v = 0.f;
            if (r < nm) {
                if (att == 0)      v = gmsk[((size_t)b*4 + r)*512 + tid];
                else if (att == 1) v = text_out[((size_t)b*256 + a0 + r)*512 + tid];
                else               v = xc2[((size_t)b*4 + r)*512 + tid];
            }
            m5[r][tid] = v;
        }
        m5[4][tid] = 0.f;
        lgam = lng[att*512 + tid]; lbet = lnb[att*512 + tid];
    }
    const float* tT = tOutT + (size_t)b*512*256;
    const float* tO = text_out + (size_t)b*256*512;
    __syncthreads();

    for (int hop = 0; hop < 9; ++hop) {
        {
            int t = tid & 255, hq = tid >> 8;
            float a5[5] = {0.f, 0.f, 0.f, 0.f, 0.f};
            const float* tp = tT + (size_t)(hq*128)*256 + t;
            for (int h = 0; h < 128; ++h) {
                float v = tp[(size_t)h*256];
                int hh = hq*128 + h;
                #pragma unroll
                for (int r = 0; r < 5; ++r) a5[r] = fmaf(m5[r][hh], v, a5[r]);
            }
            #pragma unroll
            for (int r = 0; r < 5; ++r) part[(hq*5 + r)*256 + t] = a5[r];
        }
        __syncthreads();
        for (int idx = tid; idx < 1280; idx += 1024) {
            int r = idx >> 8, t2 = idx & 255;
            alpha[r][t2] = part[(0*5+r)*256+t2] + part[(1*5+r)*256+t2]
                         + part[(2*5+r)*256+t2] + part[(3*5+r)*256+t2];
        }
        __syncthreads();
        {
            int hh = tid & 511, hf2 = tid >> 9;
            float a5[5] = {0.f, 0.f, 0.f, 0.f, 0.f};
            const float* tp0 = tO + (size_t)(hf2*128)*512 + hh;
            for (int t = 0; t < 128; ++t) {
                float v = tp0[(size_t)t*512];
                #pragma unroll
                for (int r = 0; r < 5; ++r) a5[r] = fmaf(alpha[r][hf2*128 + t], v, a5[r]);
            }
            #pragma unroll
            for (int r = 0; r < 5; ++r) part[(hf2*5 + r)*512 + hh] = a5[r];
        }
        __syncthreads();
        #pragma unroll 1
        for (int r = 0; r < 5; ++r) {
            bool act = tid < 512;
            float xv = 0.f;
            if (act) xv = sigf(part[(0*5+r)*512 + tid] + part[(1*5+r)*512 + tid]);
            float s1 = act ? xv : 0.f;
            #pragma unroll
            for (int off = 1; off < 64; off <<= 1) s1 += __shfl_xor(s1, off);
            if ((tid & 63) == 0) red[tid >> 6] = s1;
            __syncthreads();
            float mu = (red[0]+red[1]+red[2]+red[3]+red[4]+red[5]+red[6]+red[7]) * (1.f/512.f);
            __syncthreads();
            float d = xv - mu;
            float s2 = act ? d*d : 0.f;
            #pragma unroll
            for (int off = 1; off < 64; off <<= 1) s2 += __shfl_xor(s2, off);
            if ((tid & 63) == 0) red[tid >> 6] = s2;
            __syncthreads();
            float var = (red[0]+red[1]+red[2]+red[3]+red[4]+red[5]+red[6]+red[7]) * (1.f/512.f);
            __syncthreads();
            if (act) {
                float ln = d * rsqrtf(var + 1e-12f) * lgam + lbet;
                if (r < nm || r == 4) m5[r][tid] += 0.01f * ln;
            }
        }
        __syncthreads();
    }
    if (tid < 512) {
        float ms = 0.f;
        #pragma unroll
        for (int r = 0; r < 4; ++r) if (r < nm) ms += m5[r][tid];
        ms += (float)(256 - nm) * m5[4][tid];
        msum[tid] = ms;
    }
    __syncthreads();
    {
        int t = tid & 255, hq = tid >> 8;
        float sc = 0.f;
        const float* tp = tT + (size_t)(hq*128)*256 + t;
        for (int h = 0; h < 128; ++h) sc = fmaf(msum[hq*128 + h], tp[(size_t)h*256], sc);
        part[hq*256 + t] = sc;
    }
    __syncthreads();
    float sv = -3.0e38f;
    if (tid < 256) sv = part[tid] + part[256+tid] + part[512+tid] + part[768+tid];
    float mx = sv;
    #pragma unroll
    for (int off = 1; off < 64; off <<= 1) mx = fmaxf(mx, __shfl_xor(mx, off));
    if ((tid & 63) == 0) red[tid >> 6] = mx;
    __syncthreads();
    mx = fmaxf(fmaxf(red[0], red[1]), fmaxf(red[2], red[3]));
    __syncthreads();
    float ex = (tid < 256) ? expf(sv - mx) : 0.f;
    float ss = ex;
    #pragma unroll
    for (int off = 1; off < 64; off <<= 1) ss += __shfl_xor(ss, off);
    if ((tid & 63) == 0) red[tid >> 6] = ss;
    __syncthreads();
    float tot = red[0]+red[1]+red[2]+red[3];
    __syncthreads();
    if (tid < 256) wt[tid] = ex / tot;
    __syncthreads();
    {
        int hh = tid & 511, hf2 = tid >> 9;
        float acc = 0.f;
        const float* tp0 = tO + (size_t)(hf2*128)*512 + hh;
        for (int t = 0; t < 128; ++t) acc = fmaf(wt[hf2*128 + t], tp0[(size_t)t*512], acc);
        part[hf2*512 + hh] = acc;
    }
    __syncthreads();
    if (tid < 512)
        avec[((size_t)att*32 + b)*512 + tid] = part[tid] + part[512 + tid];
}

// ---------------- final FC ----------------
__global__ __launch_bounds__(128)
void final_k(const float* __restrict__ avec, const float* __restrict__ fw,
             const float* __restrict__ fbb, float* __restrict__ out)
{
    int b = blockIdx.x, tid = threadIdx.x;
    float a0 = 0.f, a1 = 0.f, a2 = 0.f;
    for (int j = tid; j < 1536; j += 128) {
        float v = avec[((size_t)(j >> 9)*32 + b)*512 + (j & 511)];
        a0 = fmaf(v, fw[j], a0);
        a1 = fmaf(v, fw[1536 + j], a1);
        a2 = fmaf(v, fw[3072 + j], a2);
    }
    #pragma unroll
    for (int off = 1; off < 64; off <<= 1) {
        a0 += __shfl_xor(a0, off); a1 += __shfl_xor(a1, off); a2 += __shfl_xor(a2, off);
    }
    __shared__ float red[6];
    if ((tid & 63) == 0) { int w = tid >> 6; red[w] = a0; red[2+w] = a1; red[4+w] = a2; }
    __syncthreads();
    if (tid == 0) {
        out[b*3+0] = red[0] + red[1] + fbb[0];
        out[b*3+1] = red[2] + red[3] + fbb[1];
        out[b*3+2] = red[4] + red[5] + fbb[2];
    }
}

extern "C" void kernel_launch(void* const* d_in, const int* in_sizes, int n_in,
                              void* d_out, int out_size, void* d_ws, size_t ws_size,
                              hipStream_t stream)
{
    (void)in_sizes; (void)n_in; (void)out_size;
    if (ws_size < WS_NEED) return;
    const int*   ti    = (const int*)d_in[0];
    const int*   ai    = (const int*)d_in[1];
    const int*   li    = (const int*)d_in[2];
    const float* adj   = (const float*)d_in[3];
    const float* emb   = (const float*)d_in[4];
    const float* wih_f = (const float*)d_in[5];
    const float* whh_f = (const float*)d_in[6];
    const float* b_f   = (const float*)d_in[7];
    const float* wih_b = (const float*)d_in[8];
    const float* whh_b = (const float*)d_in[9];
    const float* b_b   = (const float*)d_in[10];
    const float* gcw   = (const float*)d_in[11];
    const float* gcb   = (const float*)d_in[12];
    const float* c1w   = (const float*)d_in[13];
    const float* c1b   = (const float*)d_in[14];
    const float* c2w   = (const float*)d_in[15];
    const float* c2b   = (const float*)d_in[16];
    const float* fw    = (const float*)d_in[17];
    const float* fb    = (const float*)d_in[18];
    const float* lng   = (const float*)d_in[19];
    const float* lnb   = (const float*)d_in[20];

    char* ws = (char*)d_ws;
    __half* X2h      = (__half*)(ws + OFF_X2);
    __half* pre      = (__half*)(ws + OFF_PRE);
    u32*    mb       = (u32*)(ws + OFF_MB);
    u32*    flags    = (u32*)(ws + OFF_FLG);
    float*  text_out = (float*)(ws + OFF_TOUT);
    float*  tOutT    = (float*)(ws + OFF_TOUTT);
    float*  pw_text  = (float*)(ws + OFF_PWT);
    u32*    pwtThi   = (u32*)(ws + OFF_PWTTH);
    u32*    pwtTlo   = (u32*)(ws + OFF_PWTTL);
    float*  y        = (float*)(ws + OFF_Y);
    float*  agg0     = (float*)(ws + OFF_AGG0);
    u32*    Ghi      = (u32*)(ws + OFF_GCWT);
    u32*    Glo      = (u32*)(ws + OFF_GCWT + 524288);
    float*  pwx      = (float*)(ws + OFF_PWX);
    u64*    Hs       = (u64*)(ws + OFF_PWX);   // scan-time overlay
    u32*    Wmf      = (u32*)(ws + OFF_WD);
    u32*    Wih      = (u32*)(ws + OFF_WIH);
    float*  biascat  = (float*)(ws + OFF_BIA);
    float*  w1T      = (float*)(ws + OFF_W1T);
    float*  w2T      = (float*)(ws + OFF_W2T);
    int*    meta     = (int*)(ws + OFF_META);
    float*  clf      = (float*)(ws + OFF_CLF);
    float*  denom    = (float*)(ws + OFF_DEN);
    float*  posw     = (float*)(ws + OFF_POSW);
    float*  aggm     = (float*)(ws + OFF_AGGM);
    float*  gmsk     = (float*)(ws + OFF_GMSK);
    float*  c1pw     = (float*)(ws + OFF_C1PW);
    float*  xc2      = (float*)(ws + OFF_XC2);
    float*  avec     = (float*)(ws + OFF_AVEC);

    len_k<<<1, 64, 0, stream>>>(ti, ai, li, meta, clf);
    pd_k<<<8192, 256, 0, stream>>>(adj, meta, clf, denom, posw);
    gather_k<<<8192, 128, 0, stream>>>(ti, emb, X2h);
    wpackih_k<<<2560, 256, 0, stream>>>(wih_f, wih_b, Wih);
    wmf_k<<<4096, 256, 0, stream>>>(whh_f, whh_b, Wmf);
    wtrans_k<<<dim3(3072, 2), 256, 0, stream>>>(c1w, c2w, w1T, w2T);
    hipMemcpyAsync(biascat,        b_f, 2048*4, hipMemcpyDeviceToDevice, stream);
    hipMemcpyAsync(biascat + 2048, b_b, 2048*4, hipMemcpyDeviceToDevice, stream);

    pre_mfma_k<<<dim3(64, 32), 256, 0, stream>>>((const u32*)X2h, Wih, biascat, pre);

    maskb_k<<<1, 256, 0, stream>>>(ti, mb);
    hipMemsetAsync(flags, 0, (size_t)257*128*4, stream);

    lstm_scan6_k<<<128, 256, 0, stream>>>(pre, Wmf, mb, y, flags, Hs);

    fuse_ct_k<<<dim3(8, 16, 32), 256, 0, stream>>>(y, posw, text_out, pw_text,
                                                   tOutT, pwtThi, pwtTlo);
    mmsplit_k<0, 0><<<dim3(2, 4, 32), 256, 0, stream>>>(adj, pwtThi, pwtTlo, agg0,
        512, 128, 65536L, 65536L, 131072L, nullptr, nullptr, nullptr);
    wpackg_k<<<512, 256, 0, stream>>>(gcw, Ghi, Glo);
    mmsplit_k<1, 1><<<dim3(64, 4, 1), 256, 0, stream>>>(agg0, Ghi, Glo, pwx,
        512, 256, 0L, 0L, 0L, gcb, denom, posw);

    aggm_k<<<128, 256, 0, stream>>>(adj, pwx, meta, aggm);
    gmaskn_k<<<64, 256, 0, stream>>>(aggm, gcw, gcb, meta, denom, gmsk);
    conv1n_k<<<64, 256, 0, stream>>>(pw_text, w1T, c1b, meta, posw, c1pw);
    conv2n_k<<<64, 256, 0, stream>>>(c1pw, w2T, c2b, meta, xc2);
    attend_k<<<dim3(32, 3), 1024, 0, stream>>>(text_out, tOutT, gmsk, xc2, meta, lng, lnb, avec);
    final_k<<<32, 128, 0, stream>>>(avec, fw, fb, (float*)d_out);
}